// Round 10
// baseline (6662.199 us; speedup 1.0000x reference)
//
#include <hip/hip_runtime.h>

// MHA fwd: B=4, S=2048, D_IN=D_OUT=1024, H=16, HD=64.
// FINAL DTYPES (R9-proven): ALL inputs fp32 (on-device detector returned fp32 for
// all six in R9), OUTPUT fp32 (reference returns float32; writing bf16 produced
// the bit-stable 6.1875 signature of bf16-pairs-read-as-fp32; R1's fp32-out NaN
// was the attn LDS bug, fixed in R4).
// R10: R7's audited VALU pipeline, fp32 in/out. qkv bf16, ctx fp32. Green first.

typedef __bf16 bf16x8 __attribute__((ext_vector_type(8)));

// ---------------------------------------------------------------- QKV GEMM (VALU, fp32 in, bf16 out)
// qkv[m][n] = sum_k x[m][k] * W{q,k,v}[k][n'],  n' = n & 1023, select by n >> 10.
__global__ __launch_bounds__(256) void vgemm_qkv_kernel(
        const float* __restrict__ x,  const float* __restrict__ Wq,
        const float* __restrict__ Wk, const float* __restrict__ Wv,
        __bf16* __restrict__ qkv) {
    __shared__ float sX[16][17];
    __shared__ float sW[16][17];
    int tx = threadIdx.x, ty = threadIdx.y;
    int m = blockIdx.x * 16 + ty;
    int n = blockIdx.y * 16 + tx;          // 16-wide n-tile never straddles 1024 boundary
    int wsel = (blockIdx.y * 16) >> 10;
    const float* W = (wsel == 0) ? Wq : ((wsel == 1) ? Wk : Wv);
    int nn = n & 1023;
    float acc = 0.0f;
    for (int kt = 0; kt < 64; kt++) {
        int k0 = kt * 16;
        sX[ty][tx] = x[(size_t)m * 1024 + k0 + tx];
        sW[ty][tx] = W[(size_t)(k0 + ty) * 1024 + nn];
        __syncthreads();
#pragma unroll
        for (int e = 0; e < 16; e++) acc += sX[ty][e] * sW[e][tx];
        __syncthreads();
    }
    qkv[(size_t)m * 3072 + n] = (__bf16)acc;
}

// ---------------------------------------------------------------- VALU flash attention
// QKV [8192,3072]: cols 0-1023 Q, 1024-2047 K, 2048-3071 V (head h owns 64-col slice).
// Block: 64 queries x one (b,h). 256 threads = 4 per query (16 dims each).
// ctx written FP32.
__global__ __launch_bounds__(256, 4) void attn_simple_kernel(
        const __bf16* __restrict__ QKV, float* __restrict__ ctx) {
    int qt = blockIdx.x;      // 0..31
    int bh = blockIdx.y;      // 0..63
    int b = bh >> 4, h = bh & 15;
    __shared__ __bf16 sK[64 * 72];   // [key][d]
    __shared__ __bf16 sV[64 * 72];   // [key][d]
    int tid = threadIdx.x;
    int qidx = tid >> 2;             // query within tile 0..63
    int c = tid & 3;                 // dim group: d = c*16 .. c*16+15
    int c16 = c * 16;
    int q0 = qt * 64;
    int qrow = q0 + qidx;
    const size_t hoff = (size_t)h * 64;
    const __bf16* qp = QKV + ((size_t)(b * 2048 + qrow)) * 3072 + hoff + c16;
    bf16x8 q0v = *(const bf16x8*)qp;
    bf16x8 q1v = *(const bf16x8*)(qp + 8);
    float qf[16];
#pragma unroll
    for (int e = 0; e < 8; e++) { qf[e] = (float)q0v[e]; qf[8 + e] = (float)q1v[e]; }
    float o[16] = {};
    float m_r = -1e30f, l_r = 0.0f;
    const float SC = 0.1803368801111204f;   // (1/8) * log2(e)
    int srow = tid >> 2, scol = tid & 3;    // staging: 4 thr/key, 16 dims each
    for (int kt = 0; kt <= qt; kt++) {
        int key0 = kt * 64;
        const __bf16* kp = QKV + ((size_t)(b * 2048 + key0 + srow)) * 3072 + 1024 + hoff + scol * 16;
        const __bf16* vp = kp + 1024;
        *(bf16x8*)&sK[srow * 72 + scol * 16]     = *(const bf16x8*)kp;
        *(bf16x8*)&sK[srow * 72 + scol * 16 + 8] = *(const bf16x8*)(kp + 8);
        *(bf16x8*)&sV[srow * 72 + scol * 16]     = *(const bf16x8*)vp;
        *(bf16x8*)&sV[srow * 72 + scol * 16 + 8] = *(const bf16x8*)(vp + 8);
        __syncthreads();
        for (int k_ = 0; k_ < 64; k_++) {
            bf16x8 ka = *(const bf16x8*)&sK[k_ * 72 + c16];
            bf16x8 kb = *(const bf16x8*)&sK[k_ * 72 + c16 + 8];
            float part = 0.0f;
#pragma unroll
            for (int e = 0; e < 8; e++) part += qf[e] * (float)ka[e] + qf[8 + e] * (float)kb[e];
            part += __shfl_xor(part, 1);
            part += __shfl_xor(part, 2);
            float s = part * SC;
            if (key0 + k_ > qrow) s = -1e30f;
            float mn = fmaxf(m_r, s);
            float al = exp2f(m_r - mn);
            float p  = exp2f(s - mn);
            m_r = mn;
            l_r = l_r * al + p;
            bf16x8 va = *(const bf16x8*)&sV[k_ * 72 + c16];
            bf16x8 vb = *(const bf16x8*)&sV[k_ * 72 + c16 + 8];
#pragma unroll
            for (int e = 0; e < 8; e++) {
                o[e]     = o[e]     * al + p * (float)va[e];
                o[8 + e] = o[8 + e] * al + p * (float)vb[e];
            }
        }
        __syncthreads();
    }
    float inv = 1.0f / l_r;
    float* op = ctx + ((size_t)(b * 2048 + qrow)) * 1024 + hoff + c16;
#pragma unroll
    for (int e = 0; e < 16; e++) op[e] = o[e] * inv;
}

// ---------------------------------------------------------------- output GEMM (VALU, fp32 everything)
// out[m][n] = sum_k ctx[m][k] * Wo[k][n] + bo[n]
__global__ __launch_bounds__(256) void vgemm_out_kernel(
        const float* __restrict__ ctx, const float* __restrict__ Wo,
        const float* __restrict__ bo, float* __restrict__ out) {
    __shared__ float sA[16][17];
    __shared__ float sW[16][17];
    int tx = threadIdx.x, ty = threadIdx.y;
    int m = blockIdx.x * 16 + ty;
    int n = blockIdx.y * 16 + tx;
    float acc = 0.0f;
    for (int kt = 0; kt < 64; kt++) {
        int k0 = kt * 16;
        sA[ty][tx] = ctx[(size_t)m * 1024 + k0 + tx];
        sW[ty][tx] = Wo[(size_t)(k0 + ty) * 1024 + n];
        __syncthreads();
#pragma unroll
        for (int e = 0; e < 16; e++) acc += sA[ty][e] * sW[e][tx];
        __syncthreads();
    }
    out[(size_t)m * 1024 + n] = acc + bo[n];
}

// ---------------------------------------------------------------- launch
extern "C" void kernel_launch(void* const* d_in, const int* in_sizes, int n_in,
                              void* d_out, int out_size, void* d_ws, size_t ws_size,
                              hipStream_t stream) {
    const float* x  = (const float*)d_in[0];
    const float* Wq = (const float*)d_in[1];
    const float* Wk = (const float*)d_in[2];
    const float* Wv = (const float*)d_in[3];
    const float* Wo = (const float*)d_in[4];
    const float* bo = (const float*)d_in[5];
    float* out = (float*)d_out;

    __bf16* qkv = (__bf16*)d_ws;                    // [8192,3072] bf16 = 48MB
    float*  ctx = (float*)((char*)d_ws + (size_t)25165824 * 2);  // [8192,1024] fp32 = 32MB

    vgemm_qkv_kernel<<<dim3(512, 192), dim3(16, 16), 0, stream>>>(x, Wq, Wk, Wv, qkv);
    attn_simple_kernel<<<dim3(32, 64), 256, 0, stream>>>(qkv, ctx);
    vgemm_out_kernel<<<dim3(512, 64), dim3(16, 16), 0, stream>>>(ctx, Wo, bo, out);
}

// Round 11
// 452.305 us; speedup vs baseline: 14.7294x; 14.7294x over previous
//
#include <hip/hip_runtime.h>

// MHA fwd: B=4, S=2048, D_IN=D_OUT=1024, H=16, HD=64. fp32 in / fp32 out (R10-proven).
// R11: MFMA pipeline (R5 structure, validated by R5==R6==R7==R9 output signatures):
// convert x -> bf16; transpose W -> [N,K] bf16; QKV GEMM (m97, Q pre-scaled);
// MFMA flash attention (64-q tile, online softmax base-2); out GEMM + bias -> fp32.

typedef float  f32x4  __attribute__((ext_vector_type(4)));
typedef __bf16 bf16x8 __attribute__((ext_vector_type(8)));
typedef __bf16 bf16x4 __attribute__((ext_vector_type(4)));

#define AS(n) __attribute__((address_space(n)))

__device__ __forceinline__ void gload16(const void* g, void* l) {
    __builtin_amdgcn_global_load_lds((const AS(1) void*)g, (AS(3) void*)l, 16, 0, 0);
}

__device__ __forceinline__ f32x4 mfma16(bf16x8 a, bf16x8 b, f32x4 c) {
    return __builtin_amdgcn_mfma_f32_16x16x32_bf16(a, b, c, 0, 0, 0);
}

// ---------------------------------------------------------------- x fp32 -> bf16
__global__ void convert_x_kernel(const float4* __restrict__ x, __bf16* __restrict__ xb) {
    int t = blockIdx.x * 256 + threadIdx.x;
    float4 v = x[t];
    bf16x4 o = { (__bf16)v.x, (__bf16)v.y, (__bf16)v.z, (__bf16)v.w };
    ((bf16x4*)xb)[t] = o;
}

// ---------------------------------------------------------------- weight transpose fp32 -> bf16 [N,K]
__global__ void transpose_w_kernel(const float* __restrict__ Wq, const float* __restrict__ Wk,
                                   const float* __restrict__ Wv, const float* __restrict__ Wo,
                                   __bf16* __restrict__ wqkvt, __bf16* __restrict__ wot) {
    const float* src; __bf16* dst;
    int z = blockIdx.z;
    if (z == 0)      { src = Wq; dst = wqkvt; }
    else if (z == 1) { src = Wk; dst = wqkvt + 1048576; }
    else if (z == 2) { src = Wv; dst = wqkvt + 2097152; }
    else             { src = Wo; dst = wot; }
    __shared__ float tile[32][33];
    int tx = threadIdx.x, ty = threadIdx.y;
    int x = blockIdx.x * 32 + tx;
    int y0 = blockIdx.y * 32;
#pragma unroll
    for (int i = ty; i < 32; i += 8) tile[i][tx] = src[(size_t)(y0 + i) * 1024 + x];
    __syncthreads();
    int xo = blockIdx.y * 32 + tx;    // col = k
    int yo0 = blockIdx.x * 32;        // row = n
#pragma unroll
    for (int i = ty; i < 32; i += 8) dst[(size_t)(yo0 + i) * 1024 + xo] = (__bf16)tile[tx][i];
}

// ---------------------------------------------------------------- QKV GEMM (MFMA)
// A = xb [8192,1024], Bt = wqkvt [3072,1024]. Writes Q(scaled)/K/V as [B,H,S,HD] bf16.
__global__ __launch_bounds__(256, 2) void gemm_qkv_kernel(
        const __bf16* __restrict__ A, const __bf16* __restrict__ Bt,
        __bf16* __restrict__ Qp, __bf16* __restrict__ Kp, __bf16* __restrict__ Vp) {
    __shared__ __bf16 lA[128 * 32];
    __shared__ __bf16 lB[128 * 32];
    int tid = threadIdx.x;
    int m0 = blockIdx.x * 128, n0 = blockIdx.y * 128;
    int w = tid >> 6, lane = tid & 63, quad = lane >> 4, l15 = lane & 15;
    int wm = (w & 1) * 64, wn = (w >> 1) * 64;
    f32x4 acc[4][4] = {};
    int rowS = tid >> 2, kc = tid & 3;
    const __bf16* Abase = A + (size_t)m0 * 1024;
    const __bf16* Bbase = Bt + (size_t)n0 * 1024;
    for (int kt = 0; kt < 32; kt++) {
        int k0 = kt * 32;
        gload16(Abase + (size_t)rowS * 1024 + k0 + kc * 8,        &lA[tid * 8]);
        gload16(Abase + (size_t)(rowS + 64) * 1024 + k0 + kc * 8, &lA[(tid + 256) * 8]);
        gload16(Bbase + (size_t)rowS * 1024 + k0 + kc * 8,        &lB[tid * 8]);
        gload16(Bbase + (size_t)(rowS + 64) * 1024 + k0 + kc * 8, &lB[(tid + 256) * 8]);
        __syncthreads();
        bf16x8 a[4], b[4];
#pragma unroll
        for (int i = 0; i < 4; i++) a[i] = *(const bf16x8*)&lA[(wm + i * 16 + l15) * 32 + quad * 8];
#pragma unroll
        for (int j = 0; j < 4; j++) b[j] = *(const bf16x8*)&lB[(wn + j * 16 + l15) * 32 + quad * 8];
#pragma unroll
        for (int i = 0; i < 4; i++)
#pragma unroll
            for (int j = 0; j < 4; j++)
                acc[i][j] = mfma16(a[i], b[j], acc[i][j]);
        __syncthreads();
    }
    int mat = n0 >> 10;
    int ncol0 = n0 & 1023;
    __bf16* dst = (mat == 0) ? Qp : ((mat == 1) ? Kp : Vp);
    float sc = (mat == 0) ? 0.1803368801111204f : 1.0f;  // 0.125 * log2(e) for Q
#pragma unroll
    for (int i = 0; i < 4; i++) {
#pragma unroll
        for (int j = 0; j < 4; j++) {
            int n = ncol0 + wn + j * 16 + l15;
            int h = n >> 6, d = n & 63;
#pragma unroll
            for (int r = 0; r < 4; r++) {
                int m = m0 + wm + i * 16 + quad * 4 + r;
                int bb = m >> 11, s = m & 2047;
                dst[((((size_t)bb * 16 + h) * 2048 + s) << 6) + d] = (__bf16)(acc[i][j][r] * sc);
            }
        }
    }
}

// ---------------------------------------------------------------- MFMA flash attention
// Q pre-scaled by 0.125*log2e. Per block: 64 queries, one (b,h). 4 waves x 16 rows.
__global__ __launch_bounds__(256, 2) void attn_kernel(
        const __bf16* __restrict__ Q, const __bf16* __restrict__ K,
        const __bf16* __restrict__ V, __bf16* __restrict__ ctx) {
    int qt = blockIdx.x;      // 0..31
    int bh = blockIdx.y;      // 0..63
    int b = bh >> 4, h = bh & 15;
    const __bf16* Qb = Q + (size_t)bh * 2048 * 64;
    const __bf16* Kb = K + (size_t)bh * 2048 * 64;
    const __bf16* Vb = V + (size_t)bh * 2048 * 64;
    __shared__ __bf16 sK[64 * 72];   // [key][d]
    __shared__ __bf16 sV[64 * 72];   // [d][key] (transposed)
    __shared__ __bf16 sP[64 * 72];   // [qrow][key], wave-private slices
    int tid = threadIdx.x, w = tid >> 6, lane = tid & 63, quad = lane >> 4, l15 = lane & 15;
    int q0 = qt * 64;
    int qrow = q0 + w * 16 + l15;
    bf16x8 aQ0 = *(const bf16x8*)(Qb + (size_t)qrow * 64 + quad * 8);
    bf16x8 aQ1 = *(const bf16x8*)(Qb + (size_t)qrow * 64 + 32 + quad * 8);
    f32x4 o[4] = {};
    float m_r[4] = { -1e30f, -1e30f, -1e30f, -1e30f };
    float l_r[4] = {};
    int srow = tid >> 2, scol = tid & 3;   // staging: 4 thr/key, 16 dims each
    for (int kt = 0; kt <= qt; kt++) {
        int key0 = kt * 64;
        bf16x8 ka = *(const bf16x8*)(Kb + (size_t)(key0 + srow) * 64 + scol * 16);
        bf16x8 kb = *(const bf16x8*)(Kb + (size_t)(key0 + srow) * 64 + scol * 16 + 8);
        *(bf16x8*)&sK[srow * 72 + scol * 16]     = ka;
        *(bf16x8*)&sK[srow * 72 + scol * 16 + 8] = kb;
        bf16x8 va = *(const bf16x8*)(Vb + (size_t)(key0 + srow) * 64 + scol * 16);
        bf16x8 vb = *(const bf16x8*)(Vb + (size_t)(key0 + srow) * 64 + scol * 16 + 8);
#pragma unroll
        for (int e = 0; e < 8; e++) sV[(scol * 16 + e) * 72 + srow]     = va[e];
#pragma unroll
        for (int e = 0; e < 8; e++) sV[(scol * 16 + 8 + e) * 72 + srow] = vb[e];
        __syncthreads();
        f32x4 s[4];
#pragma unroll
        for (int j = 0; j < 4; j++) {
            bf16x8 k0 = *(const bf16x8*)&sK[(j * 16 + l15) * 72 + quad * 8];
            bf16x8 k1 = *(const bf16x8*)&sK[(j * 16 + l15) * 72 + 32 + quad * 8];
            f32x4 z = {};
            z = mfma16(aQ0, k0, z);
            s[j] = mfma16(aQ1, k1, z);
        }
        if (kt == qt) {
#pragma unroll
            for (int j = 0; j < 4; j++) {
                int key = j * 16 + l15;
#pragma unroll
                for (int r = 0; r < 4; r++)
                    if (key > w * 16 + quad * 4 + r) s[j][r] = -1e30f;
            }
        }
        float alpha[4];
#pragma unroll
        for (int r = 0; r < 4; r++) {
            float mx = fmaxf(fmaxf(s[0][r], s[1][r]), fmaxf(s[2][r], s[3][r]));
            mx = fmaxf(mx, __shfl_xor(mx, 1));
            mx = fmaxf(mx, __shfl_xor(mx, 2));
            mx = fmaxf(mx, __shfl_xor(mx, 4));
            mx = fmaxf(mx, __shfl_xor(mx, 8));
            float mn = fmaxf(m_r[r], mx);
            float al = exp2f(m_r[r] - mn);
            m_r[r] = mn;
            float p0 = exp2f(s[0][r] - mn);
            float p1 = exp2f(s[1][r] - mn);
            float p2 = exp2f(s[2][r] - mn);
            float p3 = exp2f(s[3][r] - mn);
            s[0][r] = p0; s[1][r] = p1; s[2][r] = p2; s[3][r] = p3;
            float rs = (p0 + p1) + (p2 + p3);
            rs += __shfl_xor(rs, 1);
            rs += __shfl_xor(rs, 2);
            rs += __shfl_xor(rs, 4);
            rs += __shfl_xor(rs, 8);
            l_r[r] = l_r[r] * al + rs;
            alpha[r] = al;
        }
#pragma unroll
        for (int dj = 0; dj < 4; dj++) {
            o[dj][0] *= alpha[0]; o[dj][1] *= alpha[1];
            o[dj][2] *= alpha[2]; o[dj][3] *= alpha[3];
        }
        // P: C-layout -> LDS -> A-layout (wave-private rows)
#pragma unroll
        for (int j = 0; j < 4; j++)
#pragma unroll
            for (int r = 0; r < 4; r++)
                sP[(w * 16 + quad * 4 + r) * 72 + j * 16 + l15] = (__bf16)s[j][r];
        bf16x8 p0v = *(const bf16x8*)&sP[(w * 16 + l15) * 72 + quad * 8];
        bf16x8 p1v = *(const bf16x8*)&sP[(w * 16 + l15) * 72 + 32 + quad * 8];
#pragma unroll
        for (int dj = 0; dj < 4; dj++) {
            bf16x8 v0 = *(const bf16x8*)&sV[(dj * 16 + l15) * 72 + quad * 8];
            bf16x8 v1 = *(const bf16x8*)&sV[(dj * 16 + l15) * 72 + 32 + quad * 8];
            f32x4 t = mfma16(p0v, v0, o[dj]);
            o[dj] = mfma16(p1v, v1, t);
        }
        __syncthreads();
    }
#pragma unroll
    for (int r = 0; r < 4; r++) {
        float inv = 1.0f / l_r[r];
        int q = q0 + w * 16 + quad * 4 + r;
        size_t base = (((size_t)b * 2048 + q) << 10) + h * 64;
#pragma unroll
        for (int dj = 0; dj < 4; dj++)
            ctx[base + dj * 16 + l15] = (__bf16)(o[dj][r] * inv);
    }
}

// ---------------------------------------------------------------- output GEMM (MFMA, fp32 bias+out)
__global__ __launch_bounds__(256, 2) void gemm_out_kernel(
        const __bf16* __restrict__ A, const __bf16* __restrict__ Bt,
        const float* __restrict__ bo, float* __restrict__ out) {
    __shared__ __bf16 lA[128 * 32];
    __shared__ __bf16 lB[128 * 32];
    int tid = threadIdx.x;
    int m0 = blockIdx.x * 128, n0 = blockIdx.y * 128;
    int w = tid >> 6, lane = tid & 63, quad = lane >> 4, l15 = lane & 15;
    int wm = (w & 1) * 64, wn = (w >> 1) * 64;
    f32x4 acc[4][4] = {};
    int rowS = tid >> 2, kc = tid & 3;
    const __bf16* Abase = A + (size_t)m0 * 1024;
    const __bf16* Bbase = Bt + (size_t)n0 * 1024;
    for (int kt = 0; kt < 32; kt++) {
        int k0 = kt * 32;
        gload16(Abase + (size_t)rowS * 1024 + k0 + kc * 8,        &lA[tid * 8]);
        gload16(Abase + (size_t)(rowS + 64) * 1024 + k0 + kc * 8, &lA[(tid + 256) * 8]);
        gload16(Bbase + (size_t)rowS * 1024 + k0 + kc * 8,        &lB[tid * 8]);
        gload16(Bbase + (size_t)(rowS + 64) * 1024 + k0 + kc * 8, &lB[(tid + 256) * 8]);
        __syncthreads();
        bf16x8 a[4], b[4];
#pragma unroll
        for (int i = 0; i < 4; i++) a[i] = *(const bf16x8*)&lA[(wm + i * 16 + l15) * 32 + quad * 8];
#pragma unroll
        for (int j = 0; j < 4; j++) b[j] = *(const bf16x8*)&lB[(wn + j * 16 + l15) * 32 + quad * 8];
#pragma unroll
        for (int i = 0; i < 4; i++)
#pragma unroll
            for (int j = 0; j < 4; j++)
                acc[i][j] = mfma16(a[i], b[j], acc[i][j]);
        __syncthreads();
    }
#pragma unroll
    for (int j = 0; j < 4; j++) {
        int n = n0 + wn + j * 16 + l15;
        float bias = bo[n];
#pragma unroll
        for (int i = 0; i < 4; i++)
#pragma unroll
            for (int r = 0; r < 4; r++) {
                int m = m0 + wm + i * 16 + quad * 4 + r;
                out[(size_t)m * 1024 + n] = acc[i][j][r] + bias;
            }
    }
}

// ---------------------------------------------------------------- launch
extern "C" void kernel_launch(void* const* d_in, const int* in_sizes, int n_in,
                              void* d_out, int out_size, void* d_ws, size_t ws_size,
                              hipStream_t stream) {
    const float* x  = (const float*)d_in[0];
    const float* Wq = (const float*)d_in[1];
    const float* Wk = (const float*)d_in[2];
    const float* Wv = (const float*)d_in[3];
    const float* Wo = (const float*)d_in[4];
    const float* bo = (const float*)d_in[5];
    float* out = (float*)d_out;

    __bf16* ws    = (__bf16*)d_ws;
    __bf16* xb    = ws;                   // 8192*1024
    __bf16* wqkvt = xb + 8388608;         // 3*1024*1024
    __bf16* wot   = wqkvt + 3145728;      // 1024*1024
    __bf16* Qp    = wot + 1048576;        // [B,H,S,HD]
    __bf16* Kp    = Qp + 8388608;
    __bf16* Vp    = Kp + 8388608;
    __bf16* ctx   = Vp + 8388608;         // [8192,1024]

    convert_x_kernel<<<8192, 256, 0, stream>>>((const float4*)x, xb);
    transpose_w_kernel<<<dim3(32, 32, 4), dim3(32, 8), 0, stream>>>(Wq, Wk, Wv, Wo, wqkvt, wot);
    gemm_qkv_kernel<<<dim3(64, 24), 256, 0, stream>>>(xb, wqkvt, Qp, Kp, Vp);
    attn_kernel<<<dim3(32, 64), 256, 0, stream>>>(Qp, Kp, Vp, ctx);
    gemm_out_kernel<<<dim3(64, 8), 256, 0, stream>>>(ctx, wot, bo, out);
}